// Round 12
// baseline (153.883 us; speedup 1.0000x reference)
//
#include <hip/hip_runtime.h>
#include <math.h>

// Problem constants (from reference)
#define Bn   16
#define Cn   64
#define Nn   65536        // H*W = 256*256
#define Sn   64           // n-slices per batch for gram kernel
#define Ln   (Nn / Sn)    // 1024 k-elements per block (256 per wave)
#define REDn 16

typedef float    f32x4  __attribute__((ext_vector_type(4)));
typedef float    f32x16 __attribute__((ext_vector_type(16)));
typedef __fp16   fp16x2 __attribute__((ext_vector_type(2)));
typedef _Float16 f16x8  __attribute__((ext_vector_type(8)));

union half8_u {
  f16x8  v;
  fp16x2 h[4];
};

// ---------------------------------------------------------------------------
// Kernel 1: per (batch, n-slice) block:
//   so_part[c]   = sum_d (sum_{n in slice} x[b,c,n]*x[b,d,n]) * Wrow[c,d]
//   pool_part[c] = sum_{n in slice} x[b,c,n]
// Coalesced global loads into WAVE-PRIVATE LDS buffers (no main-loop barriers).
// R12: prefetch depth 3 (window ~960cyc > ~900cyc HBM latency);
//      pool via v_dot2_f32_f16 (halves pool VALU).
// ---------------------------------------------------------------------------
__global__ __launch_bounds__(256, 4) void gram_pool_kernel(
    const float* __restrict__ x, const float* __restrict__ Wrow,
    float* __restrict__ part) {
  const int b    = blockIdx.x / Sn;
  const int s    = blockIdx.x % Sn;
  const int tid  = threadIdx.x;
  const int wid  = tid >> 6;
  const int lane = tid & 63;
  const int l31  = lane & 31;
  const int lhi  = lane >> 5;
  const int rr   = lane >> 2;   // staging row-within-group (0..15)
  const int cc   = lane & 3;    // staging 16B chunk (0..3)

  const float* xb = x + (size_t)b * Cn * Nn;

  __shared__ float stage[4][Cn * 17];   // per-wave [64 rows][17] f32 (pad)
  __shared__ float corr_s[Cn][Cn + 1];
  __shared__ float pool_lds0[4][32];
  __shared__ float pool_lds1[4][32];

  float* wb = &stage[wid][0];

  const float* gsrc[4];
  int widx[4];
#pragma unroll
  for (int i = 0; i < 4; ++i) {
    const int row = 16 * i + rr;
    gsrc[i] = xb + (size_t)row * Nn + cc * 4;
    widx[i] = row * 17 + cc * 4;
  }
  const int fA = l31 * 17 + lhi * 8;          // rows 0..31
  const int fB = (l31 + 32) * 17 + lhi * 8;   // rows 32..63

  const int kw = s * Ln + wid * (Ln / 4);     // wave's k base; 16 tiles of 16

  f32x16 acc00, acc01, acc11;
#pragma unroll
  for (int r = 0; r < 16; ++r) { acc00[r] = 0.f; acc01[r] = 0.f; acc11[r] = 0.f; }
  float pool0 = 0.f, pool1 = 0.f;
  const fp16x2 one2 = {(__fp16)1.0f, (__fp16)1.0f};

  // register prefetch pipeline, 3 tiles deep
  f32x4 sA[4], sB[4], sC[4];
#pragma unroll
  for (int i = 0; i < 4; ++i) sA[i] = *(const f32x4*)(gsrc[i] + kw);
#pragma unroll
  for (int i = 0; i < 4; ++i) sB[i] = *(const f32x4*)(gsrc[i] + kw + 16);
#pragma unroll
  for (int i = 0; i < 4; ++i) sC[i] = *(const f32x4*)(gsrc[i] + kw + 32);

  auto step = [&](f32x4* stg, int t) {
    // write tile t into this wave's private LDS buffer
#pragma unroll
    for (int i = 0; i < 4; ++i) *(f32x4*)&wb[widx[i]] = stg[i];
    // prefetch tile t+3 into the same registers
    if (t < 13) {
      const int ko = kw + (t + 3) * 16;
#pragma unroll
      for (int i = 0; i < 4; ++i) stg[i] = *(const f32x4*)(gsrc[i] + ko);
    }
    // fragments for this 16-k tile (wave-local in-order LDS: no barrier)
    f32x4 a0 = *(const f32x4*)&wb[fA];
    f32x4 a1 = *(const f32x4*)&wb[fA + 4];
    f32x4 c0 = *(const f32x4*)&wb[fB];
    f32x4 c1 = *(const f32x4*)&wb[fB + 4];

    half8_u au, bu;
    au.h[0] = __builtin_amdgcn_cvt_pkrtz(a0[0], a0[1]);
    au.h[1] = __builtin_amdgcn_cvt_pkrtz(a0[2], a0[3]);
    au.h[2] = __builtin_amdgcn_cvt_pkrtz(a1[0], a1[1]);
    au.h[3] = __builtin_amdgcn_cvt_pkrtz(a1[2], a1[3]);
    bu.h[0] = __builtin_amdgcn_cvt_pkrtz(c0[0], c0[1]);
    bu.h[1] = __builtin_amdgcn_cvt_pkrtz(c0[2], c0[3]);
    bu.h[2] = __builtin_amdgcn_cvt_pkrtz(c1[0], c1[1]);
    bu.h[3] = __builtin_amdgcn_cvt_pkrtz(c1[2], c1[3]);

    // pool via packed f16 dot2 (accumulates in f32)
#pragma unroll
    for (int i = 0; i < 4; ++i) {
      pool0 = __builtin_amdgcn_fdot2(au.h[i], one2, pool0, false);
      pool1 = __builtin_amdgcn_fdot2(bu.h[i], one2, pool1, false);
    }

    // Gram quadrants: (0,0), (0,1), (1,1); (1,0) is transpose of (0,1)
    acc00 = __builtin_amdgcn_mfma_f32_32x32x16_f16(au.v, au.v, acc00, 0, 0, 0);
    acc01 = __builtin_amdgcn_mfma_f32_32x32x16_f16(au.v, bu.v, acc01, 0, 0, 0);
    acc11 = __builtin_amdgcn_mfma_f32_32x32x16_f16(bu.v, bu.v, acc11, 0, 0, 0);
  };

  // 16 tiles, 3-deep round-robin: 5 groups of 3 + tail
#pragma unroll
  for (int tp = 0; tp < 5; ++tp) {
    step(sA, 3 * tp);
    step(sB, 3 * tp + 1);
    step(sC, 3 * tp + 2);
  }
  step(sA, 15);

  // pool: lane l and l+32 hold partials for the same row (disjoint k halves)
  pool0 += __shfl_down(pool0, 32);
  pool1 += __shfl_down(pool1, 32);
  if (lane < 32) {
    pool_lds0[wid][lane] = pool0;
    pool_lds1[wid][lane] = pool1;
  }

  for (int w = 0; w < 4; ++w) {
    __syncthreads();
    if (wid == w) {
#pragma unroll
      for (int r = 0; r < 16; ++r) {
        // verified C/D layout (32x32 MFMA): col=lane&31, row=(r&3)+8*(r>>2)+4*(lane>>5)
        const int i = (r & 3) + 8 * (r >> 2) + 4 * lhi;
        const int j = l31;
        if (w == 0) {
          corr_s[i][j]           = acc00[r];
          corr_s[i][j + 32]      = acc01[r];
          corr_s[j + 32][i]      = acc01[r];   // symmetric mirror
          corr_s[i + 32][j + 32] = acc11[r];
        } else {
          corr_s[i][j]           += acc00[r];
          corr_s[i][j + 32]      += acc01[r];
          corr_s[j + 32][i]      += acc01[r];
          corr_s[i + 32][j + 32] += acc11[r];
        }
      }
    }
  }
  __syncthreads();

  if (tid < Cn) {
    const float* wr = Wrow + tid * Cn;
    float so = 0.f;
#pragma unroll 8
    for (int d = 0; d < Cn; ++d) so += corr_s[tid][d] * wr[d];
    float pp = 0.f;
    if (tid < 32) {
#pragma unroll
      for (int w = 0; w < 4; ++w) pp += pool_lds0[w][tid];
    } else {
#pragma unroll
      for (int w = 0; w < 4; ++w) pp += pool_lds1[w][tid - 32];
    }
    float* o = part + (size_t)(b * Sn + s) * (2 * Cn);
    o[tid]      = so;
    o[Cn + tid] = pp;
  }
}

// ---------------------------------------------------------------------------
// Kernel 2: per-batch reduce partials + tiny MLP -> gate g[b,c]
// ---------------------------------------------------------------------------
__global__ __launch_bounds__(64) void se_kernel(
    const float* __restrict__ part, const float* __restrict__ brow,
    const float* __restrict__ W1, const float* __restrict__ b1,
    const float* __restrict__ W2, const float* __restrict__ b2,
    float* __restrict__ g) {
  const int b = blockIdx.x;
  const int t = threadIdx.x;   // 0..63

  __shared__ float y_s[Cn];
  __shared__ float z_s[REDn];

  float so = 0.f, pl = 0.f;
  for (int s = 0; s < Sn; ++s) {
    const float* p = part + (size_t)(b * Sn + s) * (2 * Cn);
    so += p[t];
    pl += p[Cn + t];
  }
  y_s[t] = (so + pl) * (1.0f / (float)Nn) + brow[t];
  __syncthreads();

  if (t < REDn) {
    float z = b1[t];
#pragma unroll 8
    for (int c = 0; c < Cn; ++c) z += W1[t * Cn + c] * y_s[c];
    z_s[t] = fmaxf(z, 0.f);
  }
  __syncthreads();

  float a = b2[t];
#pragma unroll
  for (int r = 0; r < REDn; ++r) a += W2[t * REDn + r] * z_s[r];
  g[b * Cn + t] = 1.0f / (1.0f + expf(-a));
}

// ---------------------------------------------------------------------------
// Kernel 3: out[b,c,n] = x[b,c,n] * g[b,c]
// Each block owns ONE contiguous 64KB region inside a single (b,c) plane.
// Load-ahead register double-buffer; NT stores. (Proven in R11.)
// ---------------------------------------------------------------------------
#define SGRID 4096        // 16384 float4 per (b,c) / 4096 per block = 4 blocks/plane
__global__ __launch_bounds__(256) void scale_kernel(
    const float* __restrict__ x, const float* __restrict__ g,
    float* __restrict__ out) {
  const int    bid   = blockIdx.x;
  const size_t base4 = (size_t)bid * 4096;   // float4 index of block's region
  const float  gg    = g[bid >> 2];          // region lies in one (b,c) plane

  const f32x4* xv = (const f32x4*)x + base4;
  f32x4*       ov = (f32x4*)out + base4;
  const int t = threadIdx.x;

  f32x4 v0 = xv[t];
  f32x4 v1 = xv[t + 256];
  f32x4 v2 = xv[t + 512];
  f32x4 v3 = xv[t + 768];
#pragma unroll
  for (int it = 0; it < 4; ++it) {
    const int cur = t + it * 1024;
    f32x4 w0 = v0, w1 = v1, w2 = v2, w3 = v3;
    if (it < 3) {
      const int nxt = cur + 1024;
      v0 = xv[nxt];
      v1 = xv[nxt + 256];
      v2 = xv[nxt + 512];
      v3 = xv[nxt + 768];
    }
    w0 *= gg; w1 *= gg; w2 *= gg; w3 *= gg;
    __builtin_nontemporal_store(w0, &ov[cur]);
    __builtin_nontemporal_store(w1, &ov[cur + 256]);
    __builtin_nontemporal_store(w2, &ov[cur + 512]);
    __builtin_nontemporal_store(w3, &ov[cur + 768]);
  }
}

// ---------------------------------------------------------------------------
extern "C" void kernel_launch(void* const* d_in, const int* in_sizes, int n_in,
                              void* d_out, int out_size, void* d_ws, size_t ws_size,
                              hipStream_t stream) {
  const float* x    = (const float*)d_in[0];
  const float* Wrow = (const float*)d_in[1];
  const float* brow = (const float*)d_in[2];
  const float* W1   = (const float*)d_in[3];
  const float* b1   = (const float*)d_in[4];
  const float* W2   = (const float*)d_in[5];
  const float* b2   = (const float*)d_in[6];
  float* out = (float*)d_out;

  // partials in the FRONT of d_out (512 KB, fully overwritten by scale);
  // gate g (4 KB) in d_ws.
  float* part = (float*)d_out;
  float* g    = (float*)d_ws;

  gram_pool_kernel<<<Bn * Sn, 256, 0, stream>>>(x, Wrow, part);
  se_kernel<<<Bn, 64, 0, stream>>>(part, brow, W1, b1, W2, b2, g);
  scale_kernel<<<SGRID, 256, 0, stream>>>(x, g, out);
}